// Round 11
// baseline (196.170 us; speedup 1.0000x reference)
//
#include <hip/hip_runtime.h>

typedef __attribute__((ext_vector_type(8))) __bf16 bf16x8;
typedef __attribute__((ext_vector_type(4))) float f32x4;
typedef __attribute__((ext_vector_type(16))) float f32x16;
typedef unsigned int u32;

#define MFMA32(a, b, c) __builtin_amdgcn_mfma_f32_32x32x16_bf16((a), (b), (c), 0, 0, 0)
#define EXP2(x) __builtin_amdgcn_exp2f(x)
#define SETPRIO(n) __builtin_amdgcn_s_setprio(n)

static constexpr int Bsz = 4, C = 512, N = 2048, H = 8, DH = 64;
static constexpr int BN = Bsz * N;
static constexpr size_t BCN = (size_t)Bsz * C * N;
static constexpr float SM_C = 0.18033688011112042f;  // 0.125 * log2(e)

// async global->LDS; lds dest: wave-uniform base + lane*width
__device__ __forceinline__ void gload16(const void* g, void* lds) {
  __builtin_amdgcn_global_load_lds(
      (const __attribute__((address_space(1))) u32*)g,
      (__attribute__((address_space(3))) u32*)lds, 16, 0, 0);
}
__device__ __forceinline__ void gload4(const void* g, void* lds) {
  __builtin_amdgcn_global_load_lds(
      (const __attribute__((address_space(1))) u32*)g,
      (__attribute__((address_space(3))) u32*)lds, 4, 0, 0);
}

// packed f32x2 -> bf16x2 (RNE)
__device__ __forceinline__ u32 cvt_pk_bf16(float lo, float hi) {
  u32 r;
  asm("v_cvt_pk_bf16_f32 %0, %1, %2" : "=v"(r) : "v"(lo), "v"(hi));
  return r;
}

// in-place: a' = {a_lo, b_lo}, b' = {a_hi, b_hi} (halves = lanes 0-31 / 32-63)
__device__ __forceinline__ void permswap32(u32& a, u32& b) {
  asm volatile("v_permlane32_swap_b32 %0, %1" : "+v"(a), "+v"(b));
}

// ---------------- workspace layout ----------------
static constexpr size_t SZ_BF = (size_t)BN * C * sizeof(__bf16);
static constexpr size_t SZ_W  = (size_t)C * C * sizeof(__bf16);
static constexpr size_t SZ_ST = (size_t)Bsz * H * N * sizeof(float);
static constexpr size_t OFF_HT1  = 0;
static constexpr size_t OFF_HT2  = OFF_HT1 + SZ_BF;
static constexpr size_t OFF_Q    = OFF_HT2 + SZ_BF;
static constexpr size_t OFF_K    = OFF_Q + SZ_BF;
static constexpr size_t OFF_VT1  = OFF_K + SZ_BF;    // v1^T RAW: [bh][d][N]
static constexpr size_t OFF_VT2  = OFF_VT1 + SZ_BF;
static constexpr size_t OFF_CTX1 = OFF_VT2 + SZ_BF;
static constexpr size_t OFF_CTX2 = OFF_CTX1 + SZ_BF;
static constexpr size_t OFF_WQT  = OFF_CTX2 + SZ_BF;
static constexpr size_t OFF_WKT  = OFF_WQT + SZ_W;
static constexpr size_t OFF_WV1T = OFF_WKT + SZ_W;
static constexpr size_t OFF_WV2T = OFF_WV1T + SZ_W;
static constexpr size_t OFF_WO1T = OFF_WV2T + SZ_W;
static constexpr size_t OFF_WO2T = OFF_WO1T + SZ_W;
static constexpr size_t OFF_QS   = OFF_WO2T + SZ_W;  // per-q: 1/sum_k exp2(S*c)
static constexpr size_t OFF_KS   = OFF_QS + SZ_ST;   // per-k: 1/sum_q exp2(S*c)

// ---------------- fp32 -> bf16 tiled transpose: both x inputs, z=0..7 -------
__global__ __launch_bounds__(256) void k_tc2(const float* __restrict__ x1,
                                             const float* __restrict__ x2,
                                             __bf16* __restrict__ h1,
                                             __bf16* __restrict__ h2) {
  __shared__ __bf16 tile[64][66];
  int z = blockIdx.z;
  size_t boff = (size_t)(z & 3) * C * N;
  const float* src = (z < 4 ? x1 : x2) + boff;
  __bf16* dst = (z < 4 ? h1 : h2) + boff;
  int r0 = blockIdx.y * 64, c0 = blockIdx.x * 64;
  int t = threadIdx.x;
  int cl = t & 63, rr = t >> 6;
#pragma unroll
  for (int i = 0; i < 16; ++i) {
    int r = rr * 16 + i;
    tile[r][cl] = (__bf16)src[(size_t)(r0 + r) * N + c0 + cl];
  }
  __syncthreads();
#pragma unroll
  for (int i = 0; i < 16; ++i) {
    int c = rr * 16 + i;
    dst[(size_t)(c0 + c) * C + r0 + cl] = tile[cl][c];
  }
}

// all six 512x512 weight transposes in one dispatch (z = which weight)
struct WT6 {
  const float* src[6];
  __bf16* dst[6];
};
__global__ __launch_bounds__(256) void k_tcw(WT6 p) {
  __shared__ __bf16 tile[64][66];
  int z = blockIdx.z;
  const float* src = p.src[z];
  __bf16* dst = p.dst[z];
  int r0 = blockIdx.y * 64, c0 = blockIdx.x * 64;
  int t = threadIdx.x;
  int cl = t & 63, rr = t >> 6;
#pragma unroll
  for (int i = 0; i < 16; ++i) {
    int r = rr * 16 + i;
    tile[r][cl] = (__bf16)src[(size_t)(r0 + r) * C + c0 + cl];
  }
  __syncthreads();
#pragma unroll
  for (int i = 0; i < 16; ++i) {
    int c = rr * 16 + i;
    dst[(size_t)(c0 + c) * C + r0 + cl] = tile[cl][c];
  }
}

// ---------------- QKV GEMM: 4 sub-problems, 1024 blocks, single-buf BK=64 ---
// mode 0: bf16 q/k layout [bh][n][64], out = (acc+bias)*scale
// mode 1: bf16 v^T RAW layout [bh][d][N], out = acc+bias
struct GArgs4 {
  const __bf16* A; const __bf16* Bt; const float* bias;
  __bf16* outb; float scale; int mode;
};

__global__ __launch_bounds__(256, 4) void k_gemm4(GArgs4 g0, GArgs4 g1,
                                                  GArgs4 g2, GArgs4 g3) {
  __shared__ __bf16 As[128 * 64];
  __shared__ __bf16 Bs[128 * 64];
  int lin = blockIdx.x;  // 0..1023
  int swz = (lin & 7) * 128 + (lin >> 3);
  int sub = swz >> 8;
  int inner = swz & 255;
  GArgs4 ga = (sub == 0) ? g0 : (sub == 1) ? g1 : (sub == 2) ? g2 : g3;
  int m0 = (inner & 63) * 128, n0 = (inner >> 6) * 128;
  int t = threadIdx.x, lane = t & 63, w = t >> 6;
  int wm = w >> 1, wn = w & 1;
  int l31 = lane & 31, hi = lane >> 5;
  int srow = t >> 3;
  int sc8 = ((t & 7) ^ (srow & 7)) * 8;  // pre-swizzled source col (elems)
  int swA = (l31 & 7) << 4;
  int aoff0 = (wm * 64 + l31) * 128;
  int aoff1 = (wm * 64 + 32 + l31) * 128;
  int boff0 = (wn * 64 + l31) * 128;
  int boff1 = (wn * 64 + 32 + l31) * 128;
  f32x16 acc[2][2] = {};

  for (int ks = 0; ks < 8; ++ks) {
    int k0 = ks * 64;
#pragma unroll
    for (int gI = 0; gI < 4; ++gI) {
      int row_ = gI * 32 + srow;
      gload16(&ga.A[(size_t)(m0 + row_) * C + k0 + sc8],
              (char*)As + gI * 4096 + w * 1024);
      gload16(&ga.Bt[(size_t)(n0 + row_) * C + k0 + sc8],
              (char*)Bs + gI * 4096 + w * 1024);
    }
    __syncthreads();
    const char* ab = (const char*)As;
    const char* bb = (const char*)Bs;
#pragma unroll
    for (int kk = 0; kk < 4; ++kk) {
      int ko = (kk * 32 + hi * 16) ^ swA;
      bf16x8 a0 = *(const bf16x8*)(ab + aoff0 + ko);
      bf16x8 a1 = *(const bf16x8*)(ab + aoff1 + ko);
      bf16x8 b0 = *(const bf16x8*)(bb + boff0 + ko);
      bf16x8 b1 = *(const bf16x8*)(bb + boff1 + ko);
      acc[0][0] = MFMA32(a0, b0, acc[0][0]);
      acc[0][1] = MFMA32(a0, b1, acc[0][1]);
      acc[1][0] = MFMA32(a1, b0, acc[1][0]);
      acc[1][1] = MFMA32(a1, b1, acc[1][1]);
    }
    __syncthreads();
  }
#pragma unroll
  for (int mi = 0; mi < 2; ++mi)
#pragma unroll
    for (int ni = 0; ni < 2; ++ni) {
      int gn = n0 + wn * 64 + ni * 32 + l31;
      float bv = ga.bias[gn];
      int h = gn >> 6, d = gn & 63;
#pragma unroll
      for (int g2 = 0; g2 < 4; ++g2) {
        int gm = m0 + wm * 64 + mi * 32 + 8 * g2 + 4 * hi;  // 4 consecutive tokens
        int b = gm >> 11, n = gm & 2047;
        if (ga.mode == 0) {
          size_t base = (size_t)(b * 8 + h) * 2048 + n;
#pragma unroll
          for (int j = 0; j < 4; ++j)
            ga.outb[(base + j) * 64 + d] =
                (__bf16)((acc[mi][ni][4 * g2 + j] + bv) * ga.scale);
        } else {
          size_t addr = ((size_t)(b * 8 + h) * 64 + d) * 2048 + n;
          union { __bf16 h4[4]; uint2 u; } pk;
#pragma unroll
          for (int j = 0; j < 4; ++j)
            pk.h4[j] = (__bf16)(acc[mi][ni][4 * g2 + j] + bv);
          *reinterpret_cast<uint2*>(&ga.outb[addr]) = pk.u;
        }
      }
    }
}

// ---------------- O GEMM: 128x128 tile, BK=64, dbuf (2 dirs, 512 blocks) ----
struct GArgsO {
  const __bf16* A; const __bf16* Bt; const float* bias;
  float* outf; const float* resid;
};

__global__ __launch_bounds__(256, 2) void k_gemmO(GArgsO g0, GArgsO g1) {
  __shared__ __bf16 As[2 * 128 * 64];
  __shared__ __bf16 Bs[2 * 128 * 64];
  int lin = blockIdx.x;  // 0..511
  int swz = (lin & 7) * 64 + (lin >> 3);
  int dir = swz >> 8;
  int inner = swz & 255;
  const __bf16* Ap = dir ? g1.A : g0.A;
  const __bf16* Bp = dir ? g1.Bt : g0.Bt;
  const float* bias = dir ? g1.bias : g0.bias;
  float* outf = dir ? g1.outf : g0.outf;
  const float* resid = dir ? g1.resid : g0.resid;
  int m0 = (inner & 63) * 128, n0 = (inner >> 6) * 128;
  int t = threadIdx.x, lane = t & 63, w = t >> 6;
  int wm = w >> 1, wn = w & 1;
  int l31 = lane & 31, hi = lane >> 5;
  int srow = t >> 3;
  int sc8 = ((t & 7) ^ (srow & 7)) * 8;
  int swA = (l31 & 7) << 4;
  int aoff0 = (wm * 64 + l31) * 128;
  int aoff1 = (wm * 64 + 32 + l31) * 128;
  int boff0 = (wn * 64 + l31) * 128;
  int boff1 = (wn * 64 + 32 + l31) * 128;
  f32x16 acc[2][2] = {};

#define OSTAGE(p, k0)                                                        \
  {                                                                          \
    _Pragma("unroll") for (int gI = 0; gI < 4; ++gI) {                       \
      int row_ = gI * 32 + srow;                                             \
      gload16(&Ap[(size_t)(m0 + row_) * C + (k0) + sc8],                     \
              (char*)As + (p) * 16384 + gI * 4096 + w * 1024);               \
      gload16(&Bp[(size_t)(n0 + row_) * C + (k0) + sc8],                     \
              (char*)Bs + (p) * 16384 + gI * 4096 + w * 1024);               \
    }                                                                        \
  }

  OSTAGE(0, 0)
  __syncthreads();
  for (int ks = 0; ks < 8; ++ks) {
    int p = ks & 1;
    if (ks < 7) OSTAGE(p ^ 1, (ks + 1) * 64)
    const char* ab = (const char*)As + p * 16384;
    const char* bb = (const char*)Bs + p * 16384;
#pragma unroll
    for (int kk = 0; kk < 4; ++kk) {
      int ko = (kk * 32 + hi * 16) ^ swA;
      bf16x8 a0 = *(const bf16x8*)(ab + aoff0 + ko);
      bf16x8 a1 = *(const bf16x8*)(ab + aoff1 + ko);
      bf16x8 b0 = *(const bf16x8*)(bb + boff0 + ko);
      bf16x8 b1 = *(const bf16x8*)(bb + boff1 + ko);
      acc[0][0] = MFMA32(a0, b0, acc[0][0]);
      acc[0][1] = MFMA32(a0, b1, acc[0][1]);
      acc[1][0] = MFMA32(a1, b0, acc[1][0]);
      acc[1][1] = MFMA32(a1, b1, acc[1][1]);
    }
    __syncthreads();
  }
#pragma unroll
  for (int mi = 0; mi < 2; ++mi)
#pragma unroll
    for (int ni = 0; ni < 2; ++ni) {
      int gn = n0 + wn * 64 + ni * 32 + l31;
      float bv = bias[gn];
#pragma unroll
      for (int g2 = 0; g2 < 4; ++g2) {
        int gm = m0 + wm * 64 + mi * 32 + 8 * g2 + 4 * hi;
        int b = gm >> 11, n = gm & 2047;
        size_t addr = ((size_t)b * C + gn) * 2048 + n;
        float4 xv = *reinterpret_cast<const float4*>(&resid[addr]);
        float4 ov;
        ov.x = acc[mi][ni][4 * g2 + 0] + bv + xv.x;
        ov.y = acc[mi][ni][4 * g2 + 1] + bv + xv.y;
        ov.z = acc[mi][ni][4 * g2 + 2] + bv + xv.z;
        ov.w = acc[mi][ni][4 * g2 + 3] + bv + xv.w;
        *reinterpret_cast<float4*>(&outf[addr]) = ov;
      }
    }
}

// ---------------- stats: 1/sum over Y-rows of exp2(S), 32 q/wave ------------
// grid 1024 = 2 dir x 32 bh x 16 xblk; writes RECIPROCAL sums.
struct SArgs { const __bf16* X; const __bf16* Y; float* ors; };

__global__ __launch_bounds__(256, 6) void k_stats(SArgs sa0, SArgs sa1) {
  __shared__ __bf16 Ys[2 * 64 * 64];
  int lin = blockIdx.x;  // 0..1023
  int swz = (lin & 7) * 128 + (lin >> 3);
  int dir = swz >> 9;
  int inner = swz & 511;
  const __bf16* X = dir ? sa1.X : sa0.X;
  const __bf16* Y = dir ? sa1.Y : sa0.Y;
  float* ors = dir ? sa1.ors : sa0.ors;
  int bh = inner >> 4, xblk = inner & 15;
  int t = threadIdx.x, lane = t & 63, w = t >> 6;
  int l31 = lane & 31, hi = lane >> 5;
  const __bf16* Xb = X + (size_t)bh * N * DH;
  const __bf16* Yb = Y + (size_t)bh * N * DH;
  int qg = xblk * 128 + w * 32 + l31;
  bf16x8 xq[4];
#pragma unroll
  for (int kk = 0; kk < 4; ++kk)
    xq[kk] = *(const bf16x8*)&Xb[(size_t)qg * DH + kk * 16 + hi * 8];
  int srow = t >> 3;
  int sc8 = ((t & 7) ^ (srow & 7)) * 8;
  int ybase = l31 * 128;
  int sw = (l31 & 7) << 4;
#define SSTAGE(p, kc2)                                                       \
  {                                                                          \
    char* yb_ = (char*)Ys + (p) * 8192 + w * 1024;                           \
    gload16(&Yb[(size_t)((kc2) + srow) * DH + sc8], yb_);                    \
    gload16(&Yb[(size_t)((kc2) + 32 + srow) * DH + sc8], yb_ + 4096);        \
  }
  float sa_ = 0.f, sb_ = 0.f;
  SSTAGE(0, 0)
  __syncthreads();
  for (int it = 0; it < 32; ++it) {
    int p = it & 1;
    if (it < 31) SSTAGE(p ^ 1, (it + 1) * 64)
    const char* yb = (const char*)Ys + p * 8192;
#pragma unroll
    for (int cblk = 0; cblk < 2; ++cblk) {
      f32x16 s0 = {};
      SETPRIO(1);
#pragma unroll
      for (int kk = 0; kk < 4; ++kk) {
        bf16x8 yf = *(const bf16x8*)(yb + cblk * 4096 + ybase +
                                     ((kk * 32 + hi * 16) ^ sw));
        s0 = MFMA32(yf, xq[kk], s0);
      }
      SETPRIO(0);
#pragma unroll
      for (int e = 0; e < 8; ++e) {
        sa_ += EXP2(s0[e]);
        sb_ += EXP2(s0[e + 8]);
      }
    }
    __syncthreads();
  }
  float sum0 = sa_ + sb_;
  sum0 += __shfl_xor(sum0, 32, 64);
  if (hi == 0) ors[(size_t)bh * N + qg] = __builtin_amdgcn_rcpf(sum0);
}

// ---------------- ctx: out[q,d] = sum_c exp2(S[q,c])*rs[c] * V[c,d] ---------
// 32 q/wave, c-tile 64, LDS ~32.5 KB, grid 1024 -> 4 blocks/CU.
// rs = reciprocal column sums (1/ks for dir0, 1/qs for dir1), staged per tile.
struct CArgs {
  const __bf16* X; const __bf16* Y; const __bf16* Vt;
  const float* rs; __bf16* out;
};

__global__ __launch_bounds__(256, 4) void k_ctx(CArgs c0, CArgs c1) {
  __shared__ __bf16 Ys[2 * 64 * 64];   // [c 64][dh 64], 128B rows, swz (row&7)<<4
  __shared__ __bf16 Vs[2 * 64 * 64];   // [d 64][c 64], 128B rows, swz (row&7)<<4
  __shared__ float RsL[2][64];
  int lin = blockIdx.x;  // 0..1023
  int swz = (lin & 7) * 128 + (lin >> 3);
  int dir = swz >> 9;
  int inner = swz & 511;
  const __bf16* X = dir ? c1.X : c0.X;
  const __bf16* Y = dir ? c1.Y : c0.Y;
  const __bf16* Vt = dir ? c1.Vt : c0.Vt;
  const float* rs = dir ? c1.rs : c0.rs;
  __bf16* out = dir ? c1.out : c0.out;
  int bh = inner >> 4, xblk = inner & 15;
  int b = bh >> 3, h = bh & 7;
  int t = threadIdx.x, lane = t & 63, w = t >> 6;
  int l31 = lane & 31, hi = lane >> 5;
  const __bf16* Xb = X + (size_t)bh * N * DH;
  const __bf16* Yb = Y + (size_t)bh * N * DH;
  const __bf16* Vb = Vt + (size_t)bh * DH * N;
  const float* rb = rs + (size_t)bh * N;
  int qg = xblk * 128 + w * 32 + l31;
  bf16x8 xq[4];
#pragma unroll
  for (int kk = 0; kk < 4; ++kk)
    xq[kk] = *(const bf16x8*)&Xb[(size_t)qg * DH + kk * 16 + hi * 8];
  int srow = t >> 3;
  int sc8 = ((t & 7) ^ (srow & 7)) * 8;
  int ybase = l31 * 128;
  int sw = (l31 & 7) << 4;
#define CSTAGE(p, kc2)                                                        \
  {                                                                           \
    char* yb_ = (char*)Ys + (p) * 8192 + w * 1024;                            \
    char* vb_ = (char*)Vs + (p) * 8192 + w * 1024;                            \
    gload16(&Yb[(size_t)((kc2) + srow) * DH + sc8], yb_);                     \
    gload16(&Yb[(size_t)((kc2) + 32 + srow) * DH + sc8], yb_ + 4096);         \
    gload16(&Vb[(size_t)srow * N + (kc2) + sc8], vb_);                        \
    gload16(&Vb[(size_t)(32 + srow) * N + (kc2) + sc8], vb_ + 4096);          \
    if (w == 0) gload4(&rb[(kc2) + lane], &RsL[p][0]);                        \
  }
  f32x16 oacc[2] = {};
  CSTAGE(0, 0)
  __syncthreads();
  for (int it = 0; it < 32; ++it) {
    int p = it & 1;
    if (it < 31) CSTAGE(p ^ 1, (it + 1) * 64)
    const char* yb = (const char*)Ys + p * 8192;
    const char* vb = (const char*)Vs + p * 8192;
#pragma unroll
    for (int cblk = 0; cblk < 2; ++cblk) {
      // ---- S^T for 32 c-rows x 32 q ----
      f32x16 s0 = {};
      SETPRIO(1);
#pragma unroll
      for (int kk = 0; kk < 4; ++kk) {
        bf16x8 yf = *(const bf16x8*)(yb + cblk * 4096 + ybase +
                                     ((kk * 32 + hi * 16) ^ sw));
        s0 = MFMA32(yf, xq[kk], s0);
      }
      SETPRIO(0);
      // ---- P = exp2(S) * rs[c] packed; c_local = 8g + 4hi + {0..3} ----
      u32 wl0[4], wh0[4];
#pragma unroll
      for (int g = 0; g < 4; ++g) {
        f32x4 rv = *(const f32x4*)&RsL[p][cblk * 32 + 8 * g + 4 * hi];
        wl0[g] = cvt_pk_bf16(EXP2(s0[4 * g + 0]) * rv[0],
                             EXP2(s0[4 * g + 1]) * rv[1]);
        wh0[g] = cvt_pk_bf16(EXP2(s0[4 * g + 2]) * rv[2],
                             EXP2(s0[4 * g + 3]) * rv[3]);
      }
      // ---- PV: 2 K=16 chunks of this cblk ----
#pragma unroll
      for (int sh = 0; sh < 2; ++sh) {
        int ct = cblk * 2 + sh;
        u32 p00 = wl0[2 * sh], p01 = wl0[2 * sh + 1];
        u32 p02 = wh0[2 * sh], p03 = wh0[2 * sh + 1];
        permswap32(p00, p01);
        permswap32(p02, p03);
        union { u32 wd[4]; bf16x8 v; } pf0;
        pf0.wd[0] = p00; pf0.wd[1] = p02; pf0.wd[2] = p01; pf0.wd[3] = p03;
        SETPRIO(1);
#pragma unroll
        for (int dblk = 0; dblk < 2; ++dblk) {
          bf16x8 vf = *(const bf16x8*)(vb + (dblk * 32 + l31) * 128 +
                                       ((ct * 32 + hi * 16) ^ sw));
          oacc[dblk] = MFMA32(vf, pf0.v, oacc[dblk]);
        }
        SETPRIO(0);
      }
    }
    __syncthreads();
  }
  // ---- store: q = qg, d = dblk*32 + 8g + 4hi + m ----
#pragma unroll
  for (int dblk = 0; dblk < 2; ++dblk)
#pragma unroll
    for (int g = 0; g < 4; ++g) {
      union { __bf16 h4[4]; uint2 u; } pk;
#pragma unroll
      for (int m = 0; m < 4; ++m) pk.h4[m] = (__bf16)oacc[dblk][4 * g + m];
      int d = dblk * 32 + 8 * g + 4 * hi;
      size_t addr = ((size_t)b * N + qg) * C + h * 64 + d;
      *reinterpret_cast<uint2*>(&out[addr]) = pk.u;
    }
}

extern "C" void kernel_launch(void* const* d_in, const int* in_sizes, int n_in,
                              void* d_out, int out_size, void* d_ws, size_t ws_size,
                              hipStream_t stream) {
  (void)in_sizes; (void)n_in; (void)out_size; (void)ws_size;
  const float* x1  = (const float*)d_in[0];
  const float* x2  = (const float*)d_in[1];
  const float* Wq  = (const float*)d_in[2];
  const float* bq  = (const float*)d_in[3];
  const float* Wk  = (const float*)d_in[4];
  const float* bk  = (const float*)d_in[5];
  const float* Wv1 = (const float*)d_in[6];
  const float* bv1 = (const float*)d_in[7];
  const float* Wv2 = (const float*)d_in[8];
  const float* bv2 = (const float*)d_in[9];
  const float* Wo1 = (const float*)d_in[10];
  const float* bo1 = (const float*)d_in[11];
  const float* Wo2 = (const float*)d_in[12];
  const float* bo2 = (const float*)d_in[13];

  char* ws = (char*)d_ws;
  __bf16* ht1  = (__bf16*)(ws + OFF_HT1);
  __bf16* ht2  = (__bf16*)(ws + OFF_HT2);
  __bf16* qb   = (__bf16*)(ws + OFF_Q);
  __bf16* kb   = (__bf16*)(ws + OFF_K);
  __bf16* vt1  = (__bf16*)(ws + OFF_VT1);
  __bf16* vt2  = (__bf16*)(ws + OFF_VT2);
  __bf16* ctx1 = (__bf16*)(ws + OFF_CTX1);
  __bf16* ctx2 = (__bf16*)(ws + OFF_CTX2);
  __bf16* wqt  = (__bf16*)(ws + OFF_WQT);
  __bf16* wkt  = (__bf16*)(ws + OFF_WKT);
  __bf16* wv1t = (__bf16*)(ws + OFF_WV1T);
  __bf16* wv2t = (__bf16*)(ws + OFF_WV2T);
  __bf16* wo1t = (__bf16*)(ws + OFF_WO1T);
  __bf16* wo2t = (__bf16*)(ws + OFF_WO2T);
  float* qs = (float*)(ws + OFF_QS);
  float* ks = (float*)(ws + OFF_KS);
  float* outf = (float*)d_out;

  dim3 blk(256);
  k_tc2<<<dim3(32, 8, 8), blk, 0, stream>>>(x1, x2, ht1, ht2);
  WT6 wt;
  wt.src[0] = Wq;  wt.dst[0] = wqt;
  wt.src[1] = Wk;  wt.dst[1] = wkt;
  wt.src[2] = Wv1; wt.dst[2] = wv1t;
  wt.src[3] = Wv2; wt.dst[3] = wv2t;
  wt.src[4] = Wo1; wt.dst[4] = wo1t;
  wt.src[5] = Wo2; wt.dst[5] = wo2t;
  k_tcw<<<dim3(8, 8, 6), blk, 0, stream>>>(wt);

  // all four projections in one dispatch; q pre-scaled, V raw
  GArgs4 pq{ht1, wqt, bq, qb, SM_C, 0};
  GArgs4 pk{ht2, wkt, bk, kb, 1.0f, 0};
  GArgs4 pv1{ht1, wv1t, bv1, vt1, 0.f, 1};
  GArgs4 pv2{ht2, wv2t, bv2, vt2, 0.f, 1};
  k_gemm4<<<1024, blk, 0, stream>>>(pq, pk, pv1, pv2);

  // qs[q] = 1/sum_k exp2(S*c) ; ks[k] = 1/sum_q exp2(S*c)
  SArgs st0{qb, kb, qs};
  SArgs st1{kb, qb, ks};
  k_stats<<<1024, blk, 0, stream>>>(st0, st1);

  // ctx1[q,d] = sum_k exp2(Sc)*ks_rcp[k]*v1[k,d]; ctx2 symmetric with qs_rcp
  CArgs cc0{qb, kb, vt1, ks, ctx1};
  CArgs cc1{kb, qb, vt2, qs, ctx2};
  k_ctx<<<1024, blk, 0, stream>>>(cc0, cc1);

  GArgsO go0{ctx1, wo1t, bo1, outf, x1};
  GArgsO go1{ctx2, wo2t, bo2, outf + BCN, x2};
  k_gemmO<<<512, blk, 0, stream>>>(go0, go1);
}

// Round 12
// 189.078 us; speedup vs baseline: 1.0375x; 1.0375x over previous
//
#include <hip/hip_runtime.h>

typedef __attribute__((ext_vector_type(8))) __bf16 bf16x8;
typedef __attribute__((ext_vector_type(4))) float f32x4;
typedef __attribute__((ext_vector_type(16))) float f32x16;
typedef unsigned int u32;

#define MFMA32(a, b, c) __builtin_amdgcn_mfma_f32_32x32x16_bf16((a), (b), (c), 0, 0, 0)
#define EXP2(x) __builtin_amdgcn_exp2f(x)
#define SETPRIO(n) __builtin_amdgcn_s_setprio(n)

static constexpr int Bsz = 4, C = 512, N = 2048, H = 8, DH = 64;
static constexpr int BN = Bsz * N;
static constexpr size_t BCN = (size_t)Bsz * C * N;
static constexpr float SM_C = 0.18033688011112042f;  // 0.125 * log2(e)

// async global->LDS, 16B per lane; lds dest: wave-uniform base + lane*16
__device__ __forceinline__ void gload16(const void* g, void* lds) {
  __builtin_amdgcn_global_load_lds(
      (const __attribute__((address_space(1))) u32*)g,
      (__attribute__((address_space(3))) u32*)lds, 16, 0, 0);
}

// packed f32x2 -> bf16x2 (RNE)
__device__ __forceinline__ u32 cvt_pk_bf16(float lo, float hi) {
  u32 r;
  asm("v_cvt_pk_bf16_f32 %0, %1, %2" : "=v"(r) : "v"(lo), "v"(hi));
  return r;
}

// in-place: a' = {a_lo, b_lo}, b' = {a_hi, b_hi} (halves = lanes 0-31 / 32-63)
__device__ __forceinline__ void permswap32(u32& a, u32& b) {
  asm volatile("v_permlane32_swap_b32 %0, %1" : "+v"(a), "+v"(b));
}

// ---------------- workspace layout ----------------
static constexpr size_t SZ_BF = (size_t)BN * C * sizeof(__bf16);
static constexpr size_t SZ_W  = (size_t)C * C * sizeof(__bf16);
static constexpr size_t SZ_ST = (size_t)Bsz * H * N * sizeof(float);
static constexpr size_t OFF_HT1  = 0;
static constexpr size_t OFF_HT2  = OFF_HT1 + SZ_BF;
static constexpr size_t OFF_Q    = OFF_HT2 + SZ_BF;
static constexpr size_t OFF_K    = OFF_Q + SZ_BF;
static constexpr size_t OFF_VT1  = OFF_K + SZ_BF;    // v1^T (pre-scaled): [bh][d][N]
static constexpr size_t OFF_VT2  = OFF_VT1 + SZ_BF;
static constexpr size_t OFF_CTX1 = OFF_VT2 + SZ_BF;
static constexpr size_t OFF_CTX2 = OFF_CTX1 + SZ_BF;
static constexpr size_t OFF_WQT  = OFF_CTX2 + SZ_BF;
static constexpr size_t OFF_WKT  = OFF_WQT + SZ_W;
static constexpr size_t OFF_WV1T = OFF_WKT + SZ_W;
static constexpr size_t OFF_WV2T = OFF_WV1T + SZ_W;
static constexpr size_t OFF_WO1T = OFF_WV2T + SZ_W;
static constexpr size_t OFF_WO2T = OFF_WO1T + SZ_W;
static constexpr size_t OFF_QS   = OFF_WO2T + SZ_W;  // per-q: sum_k exp2(S*c)
static constexpr size_t OFF_KS   = OFF_QS + SZ_ST;   // per-k: sum_q exp2(S*c)

// ---------------- fp32 -> bf16 tiled transpose: both x inputs, z=0..7 -------
__global__ __launch_bounds__(256) void k_tc2(const float* __restrict__ x1,
                                             const float* __restrict__ x2,
                                             __bf16* __restrict__ h1,
                                             __bf16* __restrict__ h2) {
  __shared__ __bf16 tile[64][66];
  int z = blockIdx.z;
  size_t boff = (size_t)(z & 3) * C * N;
  const float* src = (z < 4 ? x1 : x2) + boff;
  __bf16* dst = (z < 4 ? h1 : h2) + boff;
  int r0 = blockIdx.y * 64, c0 = blockIdx.x * 64;
  int t = threadIdx.x;
  int cl = t & 63, rr = t >> 6;
#pragma unroll
  for (int i = 0; i < 16; ++i) {
    int r = rr * 16 + i;
    tile[r][cl] = (__bf16)src[(size_t)(r0 + r) * N + c0 + cl];
  }
  __syncthreads();
#pragma unroll
  for (int i = 0; i < 16; ++i) {
    int c = rr * 16 + i;
    dst[(size_t)(c0 + c) * C + r0 + cl] = tile[cl][c];
  }
}

// all six 512x512 weight transposes in one dispatch (z = which weight)
struct WT6 {
  const float* src[6];
  __bf16* dst[6];
};
__global__ __launch_bounds__(256) void k_tcw(WT6 p) {
  __shared__ __bf16 tile[64][66];
  int z = blockIdx.z;
  const float* src = p.src[z];
  __bf16* dst = p.dst[z];
  int r0 = blockIdx.y * 64, c0 = blockIdx.x * 64;
  int t = threadIdx.x;
  int cl = t & 63, rr = t >> 6;
#pragma unroll
  for (int i = 0; i < 16; ++i) {
    int r = rr * 16 + i;
    tile[r][cl] = (__bf16)src[(size_t)(r0 + r) * C + c0 + cl];
  }
  __syncthreads();
#pragma unroll
  for (int i = 0; i < 16; ++i) {
    int c = rr * 16 + i;
    dst[(size_t)(c0 + c) * C + r0 + cl] = tile[cl][c];
  }
}

// ---------------- GEMM: 128x128 tile, BK=64, MFMA32, dbuf+prefetch ----------
// two directions per dispatch (512 blocks). out = A(8192x512) @ Bt^T + bias
// MODE 0: bf16 q/k layout [bh][n][64], out = (acc+bias)*scale
// MODE 1: bf16 v^T layout [bh][d][N], out = (acc+bias)/sums[bh][token]
// MODE 2: fp32 [b][col][n] + residual
struct GArgs {
  const __bf16* A; const __bf16* Bt; const float* bias; const float* rs;
  __bf16* outb; float* outf; const float* resid; float scale;
};

template <int MODE>
__global__ __launch_bounds__(256, 2) void k_gemm(GArgs g0, GArgs g1) {
  __shared__ __bf16 As[2 * 128 * 64];
  __shared__ __bf16 Bs[2 * 128 * 64];
  int lin = blockIdx.x;  // 0..511
  int swz = (lin & 7) * 64 + (lin >> 3);
  int dir = swz >> 8;
  int inner = swz & 255;
  const __bf16* Ap = dir ? g1.A : g0.A;
  const __bf16* Bp = dir ? g1.Bt : g0.Bt;
  const float* bias = dir ? g1.bias : g0.bias;
  const float* rs = dir ? g1.rs : g0.rs;
  __bf16* outb = dir ? g1.outb : g0.outb;
  float* outf = dir ? g1.outf : g0.outf;
  const float* resid = dir ? g1.resid : g0.resid;
  float scale = dir ? g1.scale : g0.scale;
  int m0 = (inner & 63) * 128, n0 = (inner >> 6) * 128;
  int t = threadIdx.x, lane = t & 63, w = t >> 6;
  int wm = w >> 1, wn = w & 1;
  int l31 = lane & 31, hi = lane >> 5;
  int srow = t >> 3;
  int sc8 = ((t & 7) ^ (srow & 7)) * 8;  // pre-swizzled source col (elems)
  int swA = (l31 & 7) << 4;
  int aoff0 = (wm * 64 + l31) * 128;
  int aoff1 = (wm * 64 + 32 + l31) * 128;
  int boff0 = (wn * 64 + l31) * 128;
  int boff1 = (wn * 64 + 32 + l31) * 128;
  f32x16 acc[2][2] = {};

#define GSTAGE(p, k0)                                                        \
  {                                                                          \
    _Pragma("unroll") for (int gI = 0; gI < 4; ++gI) {                       \
      int row_ = gI * 32 + srow;                                             \
      gload16(&Ap[(size_t)(m0 + row_) * C + (k0) + sc8],                     \
              (char*)As + (p) * 16384 + gI * 4096 + w * 1024);               \
      gload16(&Bp[(size_t)(n0 + row_) * C + (k0) + sc8],                     \
              (char*)Bs + (p) * 16384 + gI * 4096 + w * 1024);               \
    }                                                                        \
  }

  GSTAGE(0, 0)
  __syncthreads();
  for (int ks = 0; ks < 8; ++ks) {
    int p = ks & 1;
    if (ks < 7) GSTAGE(p ^ 1, (ks + 1) * 64)
    const char* ab = (const char*)As + p * 16384;
    const char* bb = (const char*)Bs + p * 16384;
    int ko0 = (hi * 16) ^ swA;
    bf16x8 a0c = *(const bf16x8*)(ab + aoff0 + ko0);
    bf16x8 a1c = *(const bf16x8*)(ab + aoff1 + ko0);
    bf16x8 b0c = *(const bf16x8*)(bb + boff0 + ko0);
    bf16x8 b1c = *(const bf16x8*)(bb + boff1 + ko0);
#pragma unroll
    for (int kk = 0; kk < 4; ++kk) {
      bf16x8 a0n, a1n, b0n, b1n;
      if (kk < 3) {
        int ko = ((kk + 1) * 32 + hi * 16) ^ swA;
        a0n = *(const bf16x8*)(ab + aoff0 + ko);
        a1n = *(const bf16x8*)(ab + aoff1 + ko);
        b0n = *(const bf16x8*)(bb + boff0 + ko);
        b1n = *(const bf16x8*)(bb + boff1 + ko);
      }
      acc[0][0] = MFMA32(a0c, b0c, acc[0][0]);
      acc[0][1] = MFMA32(a0c, b1c, acc[0][1]);
      acc[1][0] = MFMA32(a1c, b0c, acc[1][0]);
      acc[1][1] = MFMA32(a1c, b1c, acc[1][1]);
      if (kk < 3) { a0c = a0n; a1c = a1n; b0c = b0n; b1c = b1n; }
    }
    __syncthreads();
  }
#pragma unroll
  for (int mi = 0; mi < 2; ++mi)
#pragma unroll
    for (int ni = 0; ni < 2; ++ni) {
      int gn = n0 + wn * 64 + ni * 32 + l31;
      float bv = bias[gn];
#pragma unroll
      for (int g2 = 0; g2 < 4; ++g2) {
        int gm = m0 + wm * 64 + mi * 32 + 8 * g2 + 4 * hi;  // 4 consecutive tokens
        int b = gm >> 11, n = gm & 2047;
        if (MODE == 0) {
          int h = gn >> 6, d = gn & 63;
          size_t base = (size_t)(b * 8 + h) * 2048 + n;
#pragma unroll
          for (int j = 0; j < 4; ++j)
            outb[(base + j) * 64 + d] = (__bf16)((acc[mi][ni][4 * g2 + j] + bv) * scale);
        } else if (MODE == 1) {
          int h = gn >> 6, d = gn & 63;
          size_t tok = (size_t)(b * 8 + h) * 2048 + n;
          float4 sv = *reinterpret_cast<const float4*>(&rs[tok]);
          size_t addr = ((size_t)(b * 8 + h) * 64 + d) * 2048 + n;
          union { __bf16 h4[4]; uint2 u; } pk;
          pk.h4[0] = (__bf16)((acc[mi][ni][4 * g2 + 0] + bv) * __builtin_amdgcn_rcpf(sv.x));
          pk.h4[1] = (__bf16)((acc[mi][ni][4 * g2 + 1] + bv) * __builtin_amdgcn_rcpf(sv.y));
          pk.h4[2] = (__bf16)((acc[mi][ni][4 * g2 + 2] + bv) * __builtin_amdgcn_rcpf(sv.z));
          pk.h4[3] = (__bf16)((acc[mi][ni][4 * g2 + 3] + bv) * __builtin_amdgcn_rcpf(sv.w));
          *reinterpret_cast<uint2*>(&outb[addr]) = pk.u;
        } else {
          size_t addr = ((size_t)b * C + gn) * 2048 + n;
          float4 xv = *reinterpret_cast<const float4*>(&resid[addr]);
          float4 ov;
          ov.x = acc[mi][ni][4 * g2 + 0] + bv + xv.x;
          ov.y = acc[mi][ni][4 * g2 + 1] + bv + xv.y;
          ov.z = acc[mi][ni][4 * g2 + 2] + bv + xv.z;
          ov.w = acc[mi][ni][4 * g2 + 3] + bv + xv.w;
          *reinterpret_cast<float4*>(&outf[addr]) = ov;
        }
      }
    }
}

// ---------------- stats: sum over Y-rows of exp2(S), 64 q/wave, in-lane only
// two directions per dispatch (512 blocks); writes RAW sums (rcp in V-GEMM).
struct SArgs { const __bf16* X; const __bf16* Y; float* ors; };

__global__ __launch_bounds__(256, 2) void k_stats(SArgs sa0, SArgs sa1) {
  __shared__ __bf16 Ys[2 * 64 * 64];
  int lin = blockIdx.x;  // 0..511
  int swz = (lin & 7) * 64 + (lin >> 3);
  int dir = swz >> 8;
  int inner = swz & 255;
  const __bf16* X = dir ? sa1.X : sa0.X;
  const __bf16* Y = dir ? sa1.Y : sa0.Y;
  float* ors = dir ? sa1.ors : sa0.ors;
  int bh = inner >> 3, xblk = inner & 7;
  int t = threadIdx.x, lane = t & 63, w = t >> 6;
  int l31 = lane & 31, hi = lane >> 5;
  const __bf16* Xb = X + (size_t)bh * N * DH;
  const __bf16* Yb = Y + (size_t)bh * N * DH;
  int qg = xblk * 256 + w * 64 + l31;
  bf16x8 xq[2][4];
#pragma unroll
  for (int s = 0; s < 2; ++s)
#pragma unroll
    for (int kk = 0; kk < 4; ++kk)
      xq[s][kk] = *(const bf16x8*)&Xb[(size_t)(qg + s * 32) * DH + kk * 16 + hi * 8];
  int srow = t >> 3;
  int sc8 = ((t & 7) ^ (srow & 7)) * 8;
  int ybase = l31 * 128;
  int sw = (l31 & 7) << 4;
#define SSTAGE(p, kc2)                                                       \
  {                                                                          \
    char* yb_ = (char*)Ys + (p) * 8192 + w * 1024;                           \
    gload16(&Yb[(size_t)((kc2) + srow) * DH + sc8], yb_);                    \
    gload16(&Yb[(size_t)((kc2) + 32 + srow) * DH + sc8], yb_ + 4096);        \
  }
  float sa0_ = 0.f, sb0_ = 0.f, sa1_ = 0.f, sb1_ = 0.f;
  SSTAGE(0, 0)
  __syncthreads();
  for (int it = 0; it < 32; ++it) {
    int p = it & 1;
    if (it < 31) SSTAGE(p ^ 1, (it + 1) * 64)
    const char* yb = (const char*)Ys + p * 8192;
    bf16x8 yfc[4];
#pragma unroll
    for (int kk = 0; kk < 4; ++kk)
      yfc[kk] = *(const bf16x8*)(yb + ybase + ((kk * 32 + hi * 16) ^ sw));
#pragma unroll
    for (int cblk = 0; cblk < 2; ++cblk) {
      bf16x8 yfn[4];
      if (cblk == 0) {
        const char* ybn = yb + 4096;
#pragma unroll
        for (int kk = 0; kk < 4; ++kk)
          yfn[kk] = *(const bf16x8*)(ybn + ybase + ((kk * 32 + hi * 16) ^ sw));
      }
      f32x16 s0 = {}, s1 = {};
      SETPRIO(1);
#pragma unroll
      for (int kk = 0; kk < 4; ++kk) {
        s0 = MFMA32(yfc[kk], xq[0][kk], s0);
        s1 = MFMA32(yfc[kk], xq[1][kk], s1);
      }
      SETPRIO(0);
#pragma unroll
      for (int e = 0; e < 8; ++e) {
        sa0_ += EXP2(s0[e]);
        sb0_ += EXP2(s0[e + 8]);
        sa1_ += EXP2(s1[e]);
        sb1_ += EXP2(s1[e + 8]);
      }
      if (cblk == 0) {
#pragma unroll
        for (int kk = 0; kk < 4; ++kk) yfc[kk] = yfn[kk];
      }
    }
    __syncthreads();
  }
  float sum0 = sa0_ + sb0_, sum1 = sa1_ + sb1_;
  sum0 += __shfl_xor(sum0, 32, 64);
  sum1 += __shfl_xor(sum1, 32, 64);
  if (hi == 0) {
    ors[(size_t)bh * N + qg] = sum0;
    ors[(size_t)bh * N + qg + 32] = sum1;
  }
}

// ---------------- ctx: out[q,d] = sum_c exp2(S[q,c]) * V'[c,d] --------------
// c-tile 128 (16 iters); yf one-cblk-ahead + vf early register prefetch.
struct CArgs { const __bf16* X; const __bf16* Y; const __bf16* Vt; __bf16* out; };

__global__ __launch_bounds__(256, 2) void k_ctx(CArgs c0, CArgs c1) {
  __shared__ __bf16 Ys[2 * 128 * 64];   // [c 128][dh 64], 128B rows, swz (row&7)<<4
  __shared__ __bf16 Vs[2 * 64 * 128];   // [d 64][c 128], 256B rows, swz (row&15)<<4
  int lin = blockIdx.x;  // 0..511
  int swz = (lin & 7) * 64 + (lin >> 3);
  int dir = swz >> 8;
  int inner = swz & 255;
  const __bf16* X = dir ? c1.X : c0.X;
  const __bf16* Y = dir ? c1.Y : c0.Y;
  const __bf16* Vt = dir ? c1.Vt : c0.Vt;
  __bf16* out = dir ? c1.out : c0.out;
  int bh = inner >> 3, xblk = inner & 7;
  int b = bh >> 3, h = bh & 7;
  int t = threadIdx.x, lane = t & 63, w = t >> 6;
  int l31 = lane & 31, hi = lane >> 5;
  const __bf16* Xb = X + (size_t)bh * N * DH;
  const __bf16* Yb = Y + (size_t)bh * N * DH;
  const __bf16* Vb = Vt + (size_t)bh * DH * N;
  int qg = xblk * 256 + w * 64 + l31;
  bf16x8 xq[2][4];
#pragma unroll
  for (int s = 0; s < 2; ++s)
#pragma unroll
    for (int kk = 0; kk < 4; ++kk)
      xq[s][kk] = *(const bf16x8*)&Xb[(size_t)(qg + s * 32) * DH + kk * 16 + hi * 8];
  int srow = t >> 3;                      // Y: row within 32-row group
  int sc8 = ((t & 7) ^ (srow & 7)) * 8;   // Y source col (elems)
  int vrow_s = t >> 4;                    // V: row within 16-row group (0..15)
  int vc8 = ((t & 15) ^ (vrow_s & 15)) * 8;  // V source col (elems)
  int ybase = l31 * 128;
  int vbase = l31 * 256;
  int swy = (l31 & 7) << 4;
  int swv = (l31 & 15) << 4;
#define CSTAGE(p, kc2)                                                        \
  {                                                                           \
    char* yb_ = (char*)Ys + (p) * 16384 + w * 1024;                           \
    char* vb_ = (char*)Vs + (p) * 16384 + w * 1024;                           \
    _Pragma("unroll") for (int gI = 0; gI < 4; ++gI) {                        \
      gload16(&Yb[(size_t)((kc2) + gI * 32 + srow) * DH + sc8],               \
              yb_ + gI * 4096);                                               \
      gload16(&Vb[(size_t)(gI * 16 + vrow_s) * N + (kc2) + vc8],              \
              vb_ + gI * 4096);                                               \
    }                                                                         \
  }
  f32x16 oacc[2][2] = {};
  CSTAGE(0, 0)
  __syncthreads();
  for (int it = 0; it < 16; ++it) {
    int p = it & 1;
    if (it < 15) CSTAGE(p ^ 1, (it + 1) * 128)
    const char* yb = (const char*)Ys + p * 16384;
    const char* vb = (const char*)Vs + p * 16384;
    bf16x8 yfc[4];
#pragma unroll
    for (int kk = 0; kk < 4; ++kk)
      yfc[kk] = *(const bf16x8*)(yb + ybase + ((kk * 32 + hi * 16) ^ swy));
#pragma unroll
    for (int cblk = 0; cblk < 4; ++cblk) {
      // prefetch next cblk's yf and this cblk's vf before the MFMA cluster
      bf16x8 yfn[4];
      if (cblk < 3) {
        const char* ybn = yb + (cblk + 1) * 4096;
#pragma unroll
        for (int kk = 0; kk < 4; ++kk)
          yfn[kk] = *(const bf16x8*)(ybn + ybase + ((kk * 32 + hi * 16) ^ swy));
      }
      bf16x8 vfc[2][2];
#pragma unroll
      for (int sh = 0; sh < 2; ++sh)
#pragma unroll
        for (int dblk = 0; dblk < 2; ++dblk)
          vfc[sh][dblk] = *(const bf16x8*)(vb + dblk * 8192 + vbase +
                                           (((cblk * 2 + sh) * 32 + hi * 16) ^ swv));
      // ---- S^T for 32 c-rows x 64 q ----
      f32x16 s0 = {}, s1 = {};
      SETPRIO(1);
#pragma unroll
      for (int kk = 0; kk < 4; ++kk) {
        s0 = MFMA32(yfc[kk], xq[0][kk], s0);
        s1 = MFMA32(yfc[kk], xq[1][kk], s1);
      }
      SETPRIO(0);
      // ---- P = exp2(S) packed; c_local = 8g + 4hi + {0..3} ----
      u32 wl0[4], wh0[4], wl1[4], wh1[4];
#pragma unroll
      for (int g = 0; g < 4; ++g) {
        wl0[g] = cvt_pk_bf16(EXP2(s0[4 * g + 0]), EXP2(s0[4 * g + 1]));
        wh0[g] = cvt_pk_bf16(EXP2(s0[4 * g + 2]), EXP2(s0[4 * g + 3]));
        wl1[g] = cvt_pk_bf16(EXP2(s1[4 * g + 0]), EXP2(s1[4 * g + 1]));
        wh1[g] = cvt_pk_bf16(EXP2(s1[4 * g + 2]), EXP2(s1[4 * g + 3]));
      }
      // ---- PV: 2 K=16 chunks of this cblk; vf already in registers ----
#pragma unroll
      for (int sh = 0; sh < 2; ++sh) {
        u32 p00 = wl0[2 * sh], p01 = wl0[2 * sh + 1];
        u32 p02 = wh0[2 * sh], p03 = wh0[2 * sh + 1];
        permswap32(p00, p01);
        permswap32(p02, p03);
        union { u32 wd[4]; bf16x8 v; } pf0;
        pf0.wd[0] = p00; pf0.wd[1] = p02; pf0.wd[2] = p01; pf0.wd[3] = p03;
        u32 p10 = wl1[2 * sh], p11 = wl1[2 * sh + 1];
        u32 p12 = wh1[2 * sh], p13 = wh1[2 * sh + 1];
        permswap32(p10, p11);
        permswap32(p12, p13);
        union { u32 wd[4]; bf16x8 v; } pf1;
        pf1.wd[0] = p10; pf1.wd[1] = p12; pf1.wd[2] = p11; pf1.wd[3] = p13;
        SETPRIO(1);
#pragma unroll
        for (int dblk = 0; dblk < 2; ++dblk) {
          oacc[0][dblk] = MFMA32(vfc[sh][dblk], pf0.v, oacc[0][dblk]);
          oacc[1][dblk] = MFMA32(vfc[sh][dblk], pf1.v, oacc[1][dblk]);
        }
        SETPRIO(0);
      }
      if (cblk < 3) {
#pragma unroll
        for (int kk = 0; kk < 4; ++kk) yfc[kk] = yfn[kk];
      }
    }
    __syncthreads();
  }
  // ---- store: q = qg + s*32, d = dblk*32 + 8g + 4hi + m ----
#pragma unroll
  for (int s = 0; s < 2; ++s)
#pragma unroll
    for (int dblk = 0; dblk < 2; ++dblk)
#pragma unroll
      for (int g = 0; g < 4; ++g) {
        union { __bf16 h4[4]; uint2 u; } pk;
#pragma unroll
        for (int m = 0; m < 4; ++m) pk.h4[m] = (__bf16)oacc[s][dblk][4 * g + m];
        int d = dblk * 32 + 8 * g + 4 * hi;
        size_t addr = ((size_t)b * N + qg + s * 32) * C + h * 64 + d;
        *reinterpret_cast<uint2*>(&out[addr]) = pk.u;
      }
}

extern "C" void kernel_launch(void* const* d_in, const int* in_sizes, int n_in,
                              void* d_out, int out_size, void* d_ws, size_t ws_size,
                              hipStream_t stream) {
  (void)in_sizes; (void)n_in; (void)out_size; (void)ws_size;
  const float* x1  = (const float*)d_in[0];
  const float* x2  = (const float*)d_in[1];
  const float* Wq  = (const float*)d_in[2];
  const float* bq  = (const float*)d_in[3];
  const float* Wk  = (const float*)d_in[4];
  const float* bk  = (const float*)d_in[5];
  const float* Wv1 = (const float*)d_in[6];
  const float* bv1 = (const float*)d_in[7];
  const float* Wv2 = (const float*)d_in[8];
  const float* bv2 = (const float*)d_in[9];
  const float* Wo1 = (const float*)d_in[10];
  const float* bo1 = (const float*)d_in[11];
  const float* Wo2 = (const float*)d_in[12];
  const float* bo2 = (const float*)d_in[13];

  char* ws = (char*)d_ws;
  __bf16* ht1  = (__bf16*)(ws + OFF_HT1);
  __bf16* ht2  = (__bf16*)(ws + OFF_HT2);
  __bf16* qb   = (__bf16*)(ws + OFF_Q);
  __bf16* kb   = (__bf16*)(ws + OFF_K);
  __bf16* vt1  = (__bf16*)(ws + OFF_VT1);
  __bf16* vt2  = (__bf16*)(ws + OFF_VT2);
  __bf16* ctx1 = (__bf16*)(ws + OFF_CTX1);
  __bf16* ctx2 = (__bf16*)(ws + OFF_CTX2);
  __bf16* wqt  = (__bf16*)(ws + OFF_WQT);
  __bf16* wkt  = (__bf16*)(ws + OFF_WKT);
  __bf16* wv1t = (__bf16*)(ws + OFF_WV1T);
  __bf16* wv2t = (__bf16*)(ws + OFF_WV2T);
  __bf16* wo1t = (__bf16*)(ws + OFF_WO1T);
  __bf16* wo2t = (__bf16*)(ws + OFF_WO2T);
  float* qs = (float*)(ws + OFF_QS);
  float* ks = (float*)(ws + OFF_KS);
  float* outf = (float*)d_out;

  dim3 blk(256);
  k_tc2<<<dim3(32, 8, 8), blk, 0, stream>>>(x1, x2, ht1, ht2);
  WT6 wt;
  wt.src[0] = Wq;  wt.dst[0] = wqt;
  wt.src[1] = Wk;  wt.dst[1] = wkt;
  wt.src[2] = Wv1; wt.dst[2] = wv1t;
  wt.src[3] = Wv2; wt.dst[3] = wv2t;
  wt.src[4] = Wo1; wt.dst[4] = wo1t;
  wt.src[5] = Wo2; wt.dst[5] = wo2t;
  k_tcw<<<dim3(8, 8, 6), blk, 0, stream>>>(wt);

  // q pre-scaled by 0.125*log2(e); k unscaled
  GArgs gq0{ht1, wqt, bq, nullptr, qb, nullptr, nullptr, SM_C};
  GArgs gq1{ht2, wkt, bk, nullptr, kb, nullptr, nullptr, 1.0f};
  k_gemm<0><<<512, blk, 0, stream>>>(gq0, gq1);

  // qs[q] = sum_k exp2(S*c) ; ks[k] = sum_q exp2(S*c)   (raw sums)
  SArgs st0{qb, kb, qs};
  SArgs st1{kb, qb, ks};
  k_stats<<<512, blk, 0, stream>>>(st0, st1);

  // V projections with 1/sum folded in per token: v1 scaled by 1/ks, v2 by 1/qs
  GArgs gv0{ht1, wv1t, bv1, ks, vt1, nullptr, nullptr, 0.f};
  GArgs gv1{ht2, wv2t, bv2, qs, vt2, nullptr, nullptr, 0.f};
  k_gemm<1><<<512, blk, 0, stream>>>(gv0, gv1);

  // ctx1[q,d] = sum_k exp2(Sc)*v1'[k,d]; ctx2[k,d] = sum_q exp2(Sc)*v2'[q,d]
  CArgs cc0{qb, kb, vt1, ctx1};
  CArgs cc1{kb, qb, vt2, ctx2};
  k_ctx<<<512, blk, 0, stream>>>(cc0, cc1);

  GArgs go0{ctx1, wo1t, bo1, nullptr, nullptr, outf, x1, 0.f};
  GArgs go1{ctx2, wo2t, bo2, nullptr, nullptr, outf + BCN, x2, 0.f};
  k_gemm<2><<<512, blk, 0, stream>>>(go0, go1);
}